// Round 4
// baseline (611.447 us; speedup 1.0000x reference)
//
#include <hip/hip_runtime.h>
#include <hip/hip_bf16.h>

#define NRB 39936   // B*T = 1024*39
#define BB 1024
#define TT 39
#define CC 123      // NUM_C == H
#define EMBD 256
#define PCH 136     // LDS row pitch (ush); 272B = 17*16 -> b128-aligned rows

typedef __attribute__((ext_vector_type(8))) short short8;
typedef __attribute__((ext_vector_type(4))) short shortv4;
typedef __attribute__((ext_vector_type(4))) float floatx4;
typedef unsigned short us;

__device__ __forceinline__ float rcp_(float x){ return __builtin_amdgcn_rcpf(x); }
__device__ __forceinline__ float fsig(float x){ return rcp_(1.f + __expf(-x)); }
__device__ __forceinline__ float ftanh(float x){
  float ax = __builtin_fabsf(x);
  float e = __expf(-2.f*ax);
  float r = (1.f - e) * rcp_(1.f + e);
  return __builtin_copysignf(r, x);
}
__device__ __forceinline__ us f2bf(float x){
  union { float f; unsigned u; } v; v.f = x;
  unsigned r = v.u + 0x7FFFu + ((v.u >> 16) & 1u);
  return (us)(r >> 16);
}
// native HW convert (v_cvt, RNE) for the k_mid hot loop
__device__ __forceinline__ us f2bfh(float x){
  __bf16 h = (__bf16)x;
  return __builtin_bit_cast(us, h);
}
__device__ __forceinline__ float bf2f(us u){
  union { unsigned u; float f; } v; v.u = ((unsigned)u) << 16; return v.f;
}

// async global->LDS, 16B per lane; LDS dest = wave-uniform base + lane*16
__device__ __forceinline__ void gl_lds16(void* lds, const void* g){
  __builtin_amdgcn_global_load_lds(
      (const __attribute__((address_space(1))) unsigned int*)g,
      (__attribute__((address_space(3))) unsigned int*)lds, 16, 0, 0);
}

// ---------------------------------------------------------------------------
// k_pre: fused preprocessing, block-range dispatch.
#define G_RC 6
#define G_CW 1088
#define G_CAST 2496
#define G_HCAT 1872
#define G_PRE (G_RC + G_CW + G_CAST + G_HCAT)

__global__ __launch_bounds__(256) void k_pre(
    const float* __restrict__ W_ih, const float* __restrict__ W_z,
    const float* __restrict__ W_h, const float* __restrict__ answer_W,
    const float* __restrict__ zz_W, const float* __restrict__ W_hh,
    const float* __restrict__ p1_W, const float* __restrict__ p2_W,
    const float* __restrict__ emb, const int* __restrict__ q_next,
    const float* __restrict__ qmn, const float* __restrict__ q_m,
    float* __restrict__ rtab, us* __restrict__ wts,
    us* __restrict__ p1bf, us* __restrict__ p2bf,
    us* __restrict__ qbf, us* __restrict__ Abf)
{
  const int blk = blockIdx.x, tid = threadIdx.x;
  if (blk < G_RC){
    int which = blk >> 1, j = blk & 1, h = tid;
    if (h >= CC) return;
    const float* W; int stride;
    if (which==0){ W=W_ih; stride=379; } else if (which==1){ W=W_z; stride=502; } else { W=W_h; stride=502; }
    const float* a = answer_W + j*EMBD;
    const float* w = W + (size_t)h*stride + CC;
    float acc = 0.f;
    #pragma unroll 8
    for (int i=0;i<EMBD;i++) acc += w[i]*a[i];
    rtab[(which*2+j)*128 + h] = acc;
    return;
  }
  if (blk < G_RC + G_CW){
    int i = (blk - G_RC)*256 + tid;
    if (i < 7*16384){
      int w = i >> 14, idx = i & 16383, n = idx >> 7, k = idx & 127;
      float v = 0.f;
      if (n < CC && k < CC){
        if      (w==0) v = zz_W[n*CC + k];
        else if (w==1) v = W_ih[n*379 + k];
        else if (w==2) v = W_z [n*502 + k];
        else if (w==3) v = W_h [n*502 + k];
        else if (w==4) v = W_hh[n*CC + k];
        else if (w==5) v = W_z [n*502 + 379 + k];
        else           v = W_h [n*502 + 379 + k];
      }
      wts[i] = f2bf(v);
      return;
    }
    int j = i - 7*16384;
    if (j < 256*512){
      int n = j >> 9, k = j & 511;
      float v;
      if      (k < 379) v = p1_W[n*502 + k + 123];   // emb|qmn block (orig cols 123..501)
      else if (k < 384) v = 0.f;
      else if (k < 507) v = p1_W[n*502 + (k - 384)]; // out2 block (orig cols 0..122)
      else              v = 0.f;
      p1bf[j] = f2bf(v);
      return;
    }
    j -= 256*512;
    if (j < 128*256){
      int n = j >> 8, k = j & 255;
      p2bf[j] = f2bf(n < CC ? p2_W[n*256 + k] : 0.f);
    }
    return;
  }
  if (blk < G_RC + G_CW + G_CAST){
    const size_t total = (size_t)NRB*128;
    for (size_t i = (size_t)(blk - G_RC - G_CW)*256 + tid; i < total; i += (size_t)G_CAST*256){
      int col = (int)(i & 127); size_t rp = i >> 7;
      int t = (int)(rp >> 10), b = (int)(rp & 1023);
      float v = (col < CC) ? q_m[((size_t)b*TT + t)*CC + col] : 0.f;
      qbf[i] = f2bf(v);
    }
    return;
  }
  // hcat region: chunks of 8 cols, cols [0,384)
  {
    const size_t nchunk = (size_t)NRB*48;
    for (size_t c = (size_t)(blk - G_RC - G_CW - G_CAST)*256 + tid; c < nchunk; c += (size_t)G_HCAT*256){
      size_t row = c / 48;
      int c0 = (int)(c - row*48) * 8;
      short8 o;
      if (c0 < 256){
        int qn = q_next[row];
        float4 v0 = *(const float4*)(emb + (size_t)qn*EMBD + c0);
        float4 v1 = *(const float4*)(emb + (size_t)qn*EMBD + c0 + 4);
        o[0]=f2bf(v0.x); o[1]=f2bf(v0.y); o[2]=f2bf(v0.z); o[3]=f2bf(v0.w);
        o[4]=f2bf(v1.x); o[5]=f2bf(v1.y); o[6]=f2bf(v1.z); o[7]=f2bf(v1.w);
      } else {
        int j0 = c0 - 256;
        #pragma unroll
        for (int jj=0;jj<8;jj++){
          int j = j0 + jj;
          o[jj] = (j < CC) ? f2bf(qmn[row*CC + j]) : (short)0;
        }
      }
      *(short8*)(Abf + row*512 + c0) = o;
    }
  }
}

// ---------------------------------------------------------------------------
// k_zz_elem: AB = qbf @ zzW^T + zz_b (MFMA); epilogue writes swizzled
//  x1a (A-frag order), pre2/cq (C-frag order), all bf16.
__global__ __launch_bounds__(256) void k_zz_elem(
    const us* __restrict__ X, const us* __restrict__ W,
    const float* __restrict__ zz_b,
    const float* __restrict__ q_m, const int* __restrict__ s_id,
    const int* __restrict__ e_id, const float* __restrict__ student_W,
    const float* __restrict__ k_diff_W, const float* __restrict__ e_disc_W,
    const float* __restrict__ d_t_p, const float* __restrict__ d_e_p,
    us* __restrict__ x1a, us* __restrict__ pre2, us* __restrict__ cqb)
{
  __shared__ __align__(16) us Asl[16][64][8];   // 16 KB
  const int tid = threadIdx.x, w = tid >> 6, l = tid & 63, q = l >> 4, r16 = l & 15;
  const int rTile = blockIdx.x*64;
  short8 bfr[2][4];
  #pragma unroll
  for (int nt=0;nt<2;nt++){
    int n = w*32 + nt*16 + r16;
    #pragma unroll
    for (int kt=0;kt<4;kt++)
      bfr[nt][kt] = *(const short8*)(W + (size_t)n*128 + kt*32 + q*8);
  }
  #pragma unroll
  for (int i=0;i<4;i++){
    int seg = i*4 + w;
    gl_lds16(&Asl[seg][l][0], X + (size_t)(rTile+l)*128 + seg*8);
  }
  floatx4 acc[4][2];
  #pragma unroll
  for (int mt=0;mt<4;mt++){
    #pragma unroll
    for (int nt=0;nt<2;nt++){ acc[mt][nt][0]=0.f; acc[mt][nt][1]=0.f; acc[mt][nt][2]=0.f; acc[mt][nt][3]=0.f; }
  }
  __syncthreads();
  #pragma unroll
  for (int kt=0;kt<4;kt++){
    short8 af[4];
    #pragma unroll
    for (int mt=0;mt<4;mt++) af[mt] = *(const short8*)&Asl[kt*4+q][mt*16+r16][0];
    #pragma unroll
    for (int mt=0;mt<4;mt++){
      #pragma unroll
      for (int nt=0;nt<2;nt++)
        acc[mt][nt] = __builtin_amdgcn_mfma_f32_16x16x32_bf16(af[mt], bfr[nt][kt], acc[mt][nt], 0,0,0);
    }
  }
  const float dt = d_t_p[0], de = d_e_p[0];
  float zzb[2]; int colv[2];
  #pragma unroll
  for (int nt=0;nt<2;nt++){
    int col = w*32 + nt*16 + r16; colv[nt] = col;
    zzb[nt] = (col < CC) ? zz_b[col] : 0.f;
  }
  const int t = rTile >> 10;           // rows of this block share t (1024 % 64 == 0)
  #pragma unroll
  for (int mt=0;mt<4;mt++){
    #pragma unroll
    for (int i=0;i<4;i++){
      int row = rTile + mt*16 + q*4 + i;
      int b = row & 1023;
      int g = b*TT + t;
      int btile = b >> 4, r = b & 15;
      int sid = s_id[b];
      int e   = e_id[g];
      float ed = fsig(e_disc_W[e]) * de;
      size_t base = ((size_t)t*64 + btile)*2048;
      #pragma unroll
      for (int nt=0;nt<2;nt++){
        int col = colv[nt];
        float x1v = 0.f, p2v = 0.f, cqv = 0.f;
        if (col < CC){
          float ab = acc[mt][nt][i] + zzb[nt];
          float sp = fsig(student_W[(size_t)sid*CC + col]);
          float kd = fsig(k_diff_W[(size_t)e*CC + col]);
          float qv = q_m[(size_t)g*CC + col];
          x1v = ab*sp;
          p2v = ed*(dt*sp - kd)*qv;
          cqv = ed*(1.f - dt)*qv;
        }
        x1a[base + (size_t)(((col>>5)*64 + ((col>>3)&3)*16 + r)*8) + (col&7)] = f2bf(x1v);
        size_t off = base + (size_t)(((col>>5)*64 + ((r>>2))*16 + (col&15))*8) + ((col>>4)&1)*4 + (r&3);
        pre2[off] = f2bf(p2v);
        cqb[off]  = f2bf(cqv);
      }
    }
  }
}

// ---------------------------------------------------------------------------
// k_mid: fused rnn1 + (Zx,Hx) + rnn2, ONE barrier per step.
// TWO independent 16-row groups per block (1024 threads = 16 waves =
// 4 waves/SIMD). ROUND-3 LESSON: with 56KB LDS the compiler's occupancy
// heuristic targeted 2 blocks/CU (8 waves/EU) and capped VGPR at 64 ->
// spills -> 290us. amdgpu_waves_per_eu(4,4) pins EXACTLY 4 waves/EU ->
// VGPR budget 128 (this code needs ~100), 1 block/CU. Grid = BB/32 = 32.
__global__ __launch_bounds__(1024)
__attribute__((amdgpu_waves_per_eu(4,4))) void k_mid(
    const us* __restrict__ x1a, const us* __restrict__ pre2, const us* __restrict__ cqb,
    const us* __restrict__ Wih, const us* __restrict__ Whh,
    const us* __restrict__ Wzx, const us* __restrict__ Whx,
    const us* __restrict__ Wzh, const us* __restrict__ Whh2,
    const float* __restrict__ b_ih, const float* __restrict__ b_z, const float* __restrict__ b_h,
    const float* __restrict__ W_tg, const float* __restrict__ b_tg,
    const float* __restrict__ rtab, const int* __restrict__ r_idx,
    us* __restrict__ Abf)
{
  __shared__ __align__(16) us h1s[2][2][16*PCH];
  __shared__ __align__(16) us x2s[2][2][16*PCH];
  __shared__ __align__(16) us h2s[2][2][16*PCH];
  __shared__ int rint[2][TT*16];
  const int tid = threadIdx.x;
  const int gid = tid >> 9, t5 = tid & 511;          // group 0/1, id within group
  const int w = t5 >> 6, l = tid & 63, q = l >> 4, r16 = l & 15;
  const int bbase = blockIdx.x*32 + gid*16;          // first batch row of group
  const int btile = blockIdx.x*2 + gid;              // x1a/pre2/cq tile index
  const int n = w*16 + r16;                          // output column 0..127

  short8 fih[4], fhh[4], fzx[4], fhx[4], fzh[4], fh2w[4];
  #pragma unroll
  for (int kt=0;kt<4;kt++){
    size_t wofs = (size_t)n*128 + kt*32 + q*8;
    fih[kt]  = *(const short8*)(Wih  + wofs);
    fhh[kt]  = *(const short8*)(Whh  + wofs);
    fzx[kt]  = *(const short8*)(Wzx  + wofs);
    fhx[kt]  = *(const short8*)(Whx  + wofs);
    fzh[kt]  = *(const short8*)(Wzh  + wofs);
    fh2w[kt] = *(const short8*)(Whh2 + wofs);
  }
  const bool vc = n < CC;
  const float bih = vc? b_ih[n]:0.f, bzv = vc? b_z[n]:0.f, bhv = vc? b_h[n]:0.f;
  const float wg = vc? W_tg[n]:0.f, bg = vc? b_tg[n]:0.f;
  const float r10 = vc? rtab[n]:0.f,     r11 = vc? rtab[128+n]:0.f;
  const float r20 = vc? rtab[256+n]:0.f, r21 = vc? rtab[384+n]:0.f;
  const float r30 = vc? rtab[512+n]:0.f, r31 = vc? rtab[640+n]:0.f;

  for (int i = t5; i < TT*16; i += 512)
    rint[gid][i] = r_idx[(size_t)(bbase + (i & 15))*TT + (i >> 4)];
  for (int i = t5; i < 16*PCH; i += 512){ h1s[gid][1][i] = 0; h2s[gid][1][i] = 0; }

  short8 x1c[4];
  shortv4 pc4, cc4;
  {
    size_t base = (size_t)btile*2048;   // t=0 tile
    #pragma unroll
    for (int kt=0;kt<4;kt++)
      x1c[kt] = *(const short8*)(x1a + base + (size_t)(kt*64 + q*16 + r16)*8);
    size_t cofs = base + (size_t)((w>>1)*64 + q*16 + r16)*8 + (size_t)(w&1)*4;
    pc4 = *(const shortv4*)(pre2 + cofs);
    cc4 = *(const shortv4*)(cqb + cofs);
  }
  __syncthreads();

  floatx4 accx;
  #pragma unroll
  for (int i=0;i<4;i++){ int rs = rint[gid][q*4 + i]; accx[i] = bih + (rs ? r11 : r10); }
  #pragma unroll
  for (int kt=0;kt<4;kt++)
    accx = __builtin_amdgcn_mfma_f32_16x16x32_bf16(x1c[kt], fih[kt], accx, 0,0,0);

  floatx4 hold; hold[0]=0.f; hold[1]=0.f; hold[2]=0.f; hold[3]=0.f;

  for (int t=0; t<TT; t++){
    const int pA = t & 1, pO = pA ^ 1;
    short8 x1n[4]; shortv4 pcn, ccn;
    if (t < TT-1){
      size_t base = ((size_t)(t+1)*64 + btile)*2048;
      #pragma unroll
      for (int kt=0;kt<4;kt++)
        x1n[kt] = *(const short8*)(x1a + base + (size_t)(kt*64 + q*16 + r16)*8);
      size_t cofs = base + (size_t)((w>>1)*64 + q*16 + r16)*8 + (size_t)(w&1)*4;
      pcn = *(const shortv4*)(pre2 + cofs);
      ccn = *(const shortv4*)(cqb + cofs);
    }
    // ---- stage A: h1 recurrence + x2a production (pre-barrier)
    short8 fr1[4];
    #pragma unroll
    for (int kt=0;kt<4;kt++)
      fr1[kt] = *(const short8*)&h1s[gid][pO][r16*PCH + kt*32 + q*8];
    floatx4 acc1 = accx;
    #pragma unroll
    for (int kt=0;kt<4;kt++)
      acc1 = __builtin_amdgcn_mfma_f32_16x16x32_bf16(fr1[kt], fhh[kt], acc1, 0,0,0);
    float g = fsig((float)t*wg + bg);
    #pragma unroll
    for (int i=0;i<4;i++){
      float h1v = ftanh(acc1[i]) * g;
      h1s[gid][pA][(q*4+i)*PCH + n] = f2bfh(h1v);
      float xv = bf2f((us)pc4[i]) + bf2f((us)cc4[i])*h1v;
      x2s[gid][pA][(q*4+i)*PCH + n] = f2bfh(xv);
    }
    __syncthreads();
    // ---- stage B: h2 recurrence + next-step Xp precompute (post-barrier)
    if (t >= 1 && t5 < 256){
      int row = t5 >> 4, cs = t5 & 15;
      short8 hv8 = *(const short8*)&h2s[gid][pO][row*PCH + cs*8];
      *(short8*)(Abf + ((size_t)(bbase + row)*TT + (t-1))*512 + 384 + cs*8) = hv8;
    }
    short8 fx[4], fh[4];
    #pragma unroll
    for (int kt=0;kt<4;kt++){
      fx[kt] = *(const short8*)&x2s[gid][pA][r16*PCH + kt*32 + q*8];
      fh[kt] = *(const short8*)&h2s[gid][pO][r16*PCH + kt*32 + q*8];
    }
    floatx4 az, ahh;
    #pragma unroll
    for (int i=0;i<4;i++){
      int rs = rint[gid][t*16 + q*4 + i];
      az[i]  = bzv + (rs ? r21 : r20);
      ahh[i] = bhv + (rs ? r31 : r30);
    }
    #pragma unroll
    for (int kt=0;kt<4;kt++){
      az  = __builtin_amdgcn_mfma_f32_16x16x32_bf16(fx[kt], fzx[kt], az, 0,0,0);
      az  = __builtin_amdgcn_mfma_f32_16x16x32_bf16(fh[kt], fzh[kt], az, 0,0,0);
      ahh = __builtin_amdgcn_mfma_f32_16x16x32_bf16(fx[kt], fhx[kt], ahh, 0,0,0);
      ahh = __builtin_amdgcn_mfma_f32_16x16x32_bf16(fh[kt], fh2w[kt], ahh, 0,0,0);
    }
    #pragma unroll
    for (int i=0;i<4;i++){
      float z  = fsig(az[i]);
      float th = ftanh(ahh[i]);
      hold[i] += z*(th - hold[i]);
      h2s[gid][pA][(q*4+i)*PCH + n] = f2bfh(hold[i]);
    }
    if (t < TT-1){
      #pragma unroll
      for (int i=0;i<4;i++){ int rs = rint[gid][(t+1)*16 + q*4 + i]; accx[i] = bih + (rs ? r11 : r10); }
      #pragma unroll
      for (int kt=0;kt<4;kt++)
        accx = __builtin_amdgcn_mfma_f32_16x16x32_bf16(x1n[kt], fih[kt], accx, 0,0,0);
      pc4 = pcn; cc4 = ccn;
    }
  }
  __syncthreads();
  if (t5 < 256){
    int row = t5 >> 4, cs = t5 & 15;
    short8 hv8 = *(const short8*)&h2s[gid][(TT-1)&1][row*PCH + cs*8];
    *(short8*)(Abf + ((size_t)(bbase + row)*TT + (TT-1))*512 + 384 + cs*8) = hv8;
  }
}

// ---------------------------------------------------------------------------
// k_out: o1 = sigmoid(Abf @ p1bf^T + p1_b) kept in LDS (bf16),
//        o2 = sigmoid(o1 @ p2bf^T + p2_b), out = sigmoid(o2 @ p3 + p3_b).
__global__ __launch_bounds__(256) void k_out(
    const us* __restrict__ Abf, const us* __restrict__ p1bf,
    const float* __restrict__ p1_b, const us* __restrict__ p2bf,
    const float* __restrict__ p2_b, const float* __restrict__ p3_W,
    const float* __restrict__ p3_b, float* __restrict__ out)
{
  __shared__ __align__(16) us smem[20480];   // 40 KB: Asl(4096) + Bsl(16384); o1s aliases (16896)
  __shared__ float red[64][4];
  us* Asl = smem;            // [seg<8][m<64][8]
  us* Bsl = smem + 4096;     // [seg<8][n<256][8]
  us* o1s = smem;            // [row<64][264] (aliased after phase 1)
  const int tid = threadIdx.x;
  const int w = tid >> 6, l = tid & 63;
  const int q = l >> 4, r16 = l & 15;
  const int rTile = blockIdx.x * 64;
  floatx4 acc[4][4];
  #pragma unroll
  for (int a=0;a<4;a++){
    #pragma unroll
    for (int b=0;b<4;b++){ acc[a][b][0]=0.f; acc[a][b][1]=0.f; acc[a][b][2]=0.f; acc[a][b][3]=0.f; }
  }
  for (int c = 0; c < 8; c++){
    const int k0 = c*64;
    #pragma unroll
    for (int i=0;i<2;i++){
      int u = i*256 + tid; int seg = u>>6, m = u&63;
      gl_lds16(&Asl[(seg*64 + m)*8], Abf + (size_t)(rTile+m)*512 + k0 + seg*8);
    }
    #pragma unroll
    for (int i=0;i<8;i++){
      int u = i*256 + tid; int seg = u>>8, nn = u&255;
      gl_lds16(&Bsl[(seg*256 + nn)*8], p1bf + (size_t)nn*512 + k0 + seg*8);
    }
    __syncthreads();
    #pragma unroll
    for (int ks=0; ks<2; ks++){
      int seg = ks*4 + q;
      short8 af[4], bfr[4];
      #pragma unroll
      for (int mt=0;mt<4;mt++) af[mt] = *(const short8*)&Asl[(seg*64 + mt*16 + r16)*8];
      #pragma unroll
      for (int nt=0;nt<4;nt++) bfr[nt] = *(const short8*)&Bsl[(seg*256 + w*64 + nt*16 + r16)*8];
      #pragma unroll
      for (int mt=0;mt<4;mt++){
        #pragma unroll
        for (int nt=0;nt<4;nt++)
          acc[mt][nt] = __builtin_amdgcn_mfma_f32_16x16x32_bf16(af[mt], bfr[nt], acc[mt][nt], 0,0,0);
      }
    }
    __syncthreads();
  }
  // ---- write o1 (sigmoid) into LDS, row-major pitch 264
  #pragma unroll
  for (int nt=0;nt<4;nt++){
    int col = w*64 + nt*16 + r16;
    float bb = p1_b[col];
    #pragma unroll
    for (int mt=0;mt<4;mt++){
      #pragma unroll
      for (int i=0;i<4;i++)
        o1s[(mt*16 + q*4 + i)*264 + col] = f2bf(fsig(acc[mt][nt][i] + bb));
    }
  }
  __syncthreads();
  // ---- phase 2: o2 GEMM (M=64, N=128, K=256) + p3 reduction
  short8 bf2[2][8];
  #pragma unroll
  for (int nt=0;nt<2;nt++){
    int n2 = w*32 + nt*16 + r16;
    #pragma unroll
    for (int kt=0;kt<8;kt++)
      bf2[nt][kt] = *(const short8*)(p2bf + (size_t)n2*256 + kt*32 + q*8);
  }
  floatx4 ac2[4][2];
  #pragma unroll
  for (int mt=0;mt<4;mt++){
    #pragma unroll
    for (int nt=0;nt<2;nt++){ ac2[mt][nt][0]=0.f; ac2[mt][nt][1]=0.f; ac2[mt][nt][2]=0.f; ac2[mt][nt][3]=0.f; }
  }
  #pragma unroll
  for (int kt=0;kt<8;kt++){
    short8 af[4];
    #pragma unroll
    for (int mt=0;mt<4;mt++) af[mt] = *(const short8*)&o1s[(mt*16 + r16)*264 + kt*32 + q*8];
    #pragma unroll
    for (int mt=0;mt<4;mt++){
      #pragma unroll
      for (int nt=0;nt<2;nt++)
        ac2[mt][nt] = __builtin_amdgcn_mfma_f32_16x16x32_bf16(af[mt], bf2[nt][kt], ac2[mt][nt], 0,0,0);
    }
  }
  const int n0 = w*32 + r16, n1 = n0 + 16;
  const float pb0 = (n0<CC)? p2_b[n0]:0.f, pb1 = (n1<CC)? p2_b[n1]:0.f;
  const float p30 = (n0<CC)? p3_W[n0]:0.f, p31 = (n1<CC)? p3_W[n1]:0.f;
  #pragma unroll
  for (int mt=0;mt<4;mt++){
    #pragma unroll
    for (int i=0;i<4;i++){
      float s = fsig(ac2[mt][0][i]+pb0)*p30 + fsig(ac2[mt][1][i]+pb1)*p31;
      s += __shfl_xor(s,1,16); s += __shfl_xor(s,2,16);
      s += __shfl_xor(s,4,16); s += __shfl_xor(s,8,16);
      if (r16==0) red[mt*16 + q*4 + i][w] = s;
    }
  }
  __syncthreads();
  if (tid < 64){
    float o = red[tid][0]+red[tid][1]+red[tid][2]+red[tid][3] + p3_b[0];
    out[rTile + tid] = fsig(o);
  }
}

// ---------------------------------------------------------------------------
extern "C" void kernel_launch(void* const* d_in, const int* in_sizes, int n_in,
                              void* d_out, int out_size, void* d_ws, size_t ws_size,
                              hipStream_t stream) {
  const float* q_m       = (const float*)d_in[0];
  const float* q_m_next  = (const float*)d_in[1];
  const int*   s_id      = (const int*)d_in[3];
  const int*   e_id      = (const int*)d_in[4];
  const int*   r_idx     = (const int*)d_in[5];
  const int*   q_next    = (const int*)d_in[6];
  const float* emb_problem = (const float*)d_in[8];
  const float* student_W = (const float*)d_in[9];
  const float* k_diff_W  = (const float*)d_in[10];
  const float* e_disc_W  = (const float*)d_in[11];
  const float* answer_W  = (const float*)d_in[12];
  const float* zz_W      = (const float*)d_in[13];
  const float* zz_b      = (const float*)d_in[14];
  const float* d_t       = (const float*)d_in[15];
  const float* d_e       = (const float*)d_in[16];
  const float* W_ih      = (const float*)d_in[17];
  const float* b_ih      = (const float*)d_in[18];
  const float* W_hh      = (const float*)d_in[19];
  const float* W_tg      = (const float*)d_in[21];
  const float* b_tg      = (const float*)d_in[22];
  const float* W_z       = (const float*)d_in[23];
  const float* b_z       = (const float*)d_in[24];
  const float* W_h       = (const float*)d_in[25];
  const float* b_h       = (const float*)d_in[26];
  const float* p1_W      = (const float*)d_in[27];
  const float* p1_b      = (const float*)d_in[28];
  const float* p2_W      = (const float*)d_in[29];
  const float* p2_b      = (const float*)d_in[30];
  const float* p3_W      = (const float*)d_in[31];
  const float* p3_b      = (const float*)d_in[32];

  float* ws   = (float*)d_ws;
  float* rtab = ws;                                   // 1024 f32
  us* qbf  = (us*)(ws + 1024);                        // [NRB][128]
  us* x1a  = qbf  + (size_t)NRB*128;                  // swizzled [t][btile][2048]
  us* pre2 = x1a  + (size_t)NRB*128;
  us* cqb  = pre2 + (size_t)NRB*128;
  us* Abf  = cqb  + (size_t)NRB*128;                  // [NRB][512]
  us* wts  = Abf  + (size_t)NRB*512;                  // 7*[128][128]
  us* p1bf = wts  + 7*16384;                          // [256][512]
  us* p2bf = p1bf + 256*512;                          // [128][256]

  const us* zzWbf  = wts + 0*16384;
  const us* Wih123 = wts + 1*16384;
  const us* Wz123  = wts + 2*16384;
  const us* Wh123  = wts + 3*16384;
  const us* Whhbf  = wts + 4*16384;
  const us* Wzhbf  = wts + 5*16384;
  const us* Whh2bf = wts + 6*16384;

  hipLaunchKernelGGL(k_pre, dim3(G_PRE), dim3(256), 0, stream,
                     W_ih, W_z, W_h, answer_W, zz_W, W_hh, p1_W, p2_W,
                     emb_problem, q_next, q_m_next, q_m,
                     rtab, wts, p1bf, p2bf, qbf, Abf);
  hipLaunchKernelGGL(k_zz_elem, dim3(NRB/64), dim3(256), 0, stream,
                     qbf, zzWbf, zz_b, q_m, s_id, e_id, student_W, k_diff_W,
                     e_disc_W, d_t, d_e, x1a, pre2, cqb);
  hipLaunchKernelGGL(k_mid, dim3(BB/32), dim3(1024), 0, stream,
                     x1a, pre2, cqb, Wih123, Whhbf, Wz123, Wh123, Wzhbf, Whh2bf,
                     b_ih, b_z, b_h, W_tg, b_tg, rtab, r_idx, Abf);
  hipLaunchKernelGGL(k_out, dim3(NRB/64), dim3(256), 0, stream,
                     Abf, p1bf, p1_b, p2bf, p2_b, p3_W, p3_b, (float*)d_out);
}

// Round 5
// 370.924 us; speedup vs baseline: 1.6484x; 1.6484x over previous
//
#include <hip/hip_runtime.h>
#include <hip/hip_bf16.h>

#define NRB 39936   // B*T = 1024*39
#define BB 1024
#define TT 39
#define CC 123      // NUM_C == H
#define EMBD 256
#define PCH 136     // LDS row pitch (ush); 272B = 17*16 -> b128-aligned rows

typedef __attribute__((ext_vector_type(8))) short short8;
typedef __attribute__((ext_vector_type(4))) short shortv4;
typedef __attribute__((ext_vector_type(4))) float floatx4;
typedef unsigned short us;

__device__ __forceinline__ float rcp_(float x){ return __builtin_amdgcn_rcpf(x); }
__device__ __forceinline__ float fsig(float x){ return rcp_(1.f + __expf(-x)); }
__device__ __forceinline__ float ftanh(float x){
  float ax = __builtin_fabsf(x);
  float e = __expf(-2.f*ax);
  float r = (1.f - e) * rcp_(1.f + e);
  return __builtin_copysignf(r, x);
}
__device__ __forceinline__ us f2bf(float x){
  union { float f; unsigned u; } v; v.f = x;
  unsigned r = v.u + 0x7FFFu + ((v.u >> 16) & 1u);
  return (us)(r >> 16);
}
// native HW convert (v_cvt, RNE) for the k_mid hot loop
__device__ __forceinline__ us f2bfh(float x){
  __bf16 h = (__bf16)x;
  return __builtin_bit_cast(us, h);
}
__device__ __forceinline__ float bf2f(us u){
  union { unsigned u; float f; } v; v.u = ((unsigned)u) << 16; return v.f;
}

// async global->LDS, 16B per lane; LDS dest = wave-uniform base + lane*16
__device__ __forceinline__ void gl_lds16(void* lds, const void* g){
  __builtin_amdgcn_global_load_lds(
      (const __attribute__((address_space(1))) unsigned int*)g,
      (__attribute__((address_space(3))) unsigned int*)lds, 16, 0, 0);
}

// ---------------------------------------------------------------------------
// k_pre: fused preprocessing, block-range dispatch.
#define G_RC 6
#define G_CW 1088
#define G_CAST 2496
#define G_HCAT 1872
#define G_PRE (G_RC + G_CW + G_CAST + G_HCAT)

__global__ __launch_bounds__(256) void k_pre(
    const float* __restrict__ W_ih, const float* __restrict__ W_z,
    const float* __restrict__ W_h, const float* __restrict__ answer_W,
    const float* __restrict__ zz_W, const float* __restrict__ W_hh,
    const float* __restrict__ p1_W, const float* __restrict__ p2_W,
    const float* __restrict__ emb, const int* __restrict__ q_next,
    const float* __restrict__ qmn, const float* __restrict__ q_m,
    float* __restrict__ rtab, us* __restrict__ wts,
    us* __restrict__ p1bf, us* __restrict__ p2bf,
    us* __restrict__ qbf, us* __restrict__ Abf)
{
  const int blk = blockIdx.x, tid = threadIdx.x;
  if (blk < G_RC){
    int which = blk >> 1, j = blk & 1, h = tid;
    if (h >= CC) return;
    const float* W; int stride;
    if (which==0){ W=W_ih; stride=379; } else if (which==1){ W=W_z; stride=502; } else { W=W_h; stride=502; }
    const float* a = answer_W + j*EMBD;
    const float* w = W + (size_t)h*stride + CC;
    float acc = 0.f;
    #pragma unroll 8
    for (int i=0;i<EMBD;i++) acc += w[i]*a[i];
    rtab[(which*2+j)*128 + h] = acc;
    return;
  }
  if (blk < G_RC + G_CW){
    int i = (blk - G_RC)*256 + tid;
    if (i < 7*16384){
      int w = i >> 14, idx = i & 16383, n = idx >> 7, k = idx & 127;
      float v = 0.f;
      if (n < CC && k < CC){
        if      (w==0) v = zz_W[n*CC + k];
        else if (w==1) v = W_ih[n*379 + k];
        else if (w==2) v = W_z [n*502 + k];
        else if (w==3) v = W_h [n*502 + k];
        else if (w==4) v = W_hh[n*CC + k];
        else if (w==5) v = W_z [n*502 + 379 + k];
        else           v = W_h [n*502 + 379 + k];
      }
      wts[i] = f2bf(v);
      return;
    }
    int j = i - 7*16384;
    if (j < 256*512){
      int n = j >> 9, k = j & 511;
      float v;
      if      (k < 379) v = p1_W[n*502 + k + 123];   // emb|qmn block (orig cols 123..501)
      else if (k < 384) v = 0.f;
      else if (k < 507) v = p1_W[n*502 + (k - 384)]; // out2 block (orig cols 0..122)
      else              v = 0.f;
      p1bf[j] = f2bf(v);
      return;
    }
    j -= 256*512;
    if (j < 128*256){
      int n = j >> 8, k = j & 255;
      p2bf[j] = f2bf(n < CC ? p2_W[n*256 + k] : 0.f);
    }
    return;
  }
  if (blk < G_RC + G_CW + G_CAST){
    const size_t total = (size_t)NRB*128;
    for (size_t i = (size_t)(blk - G_RC - G_CW)*256 + tid; i < total; i += (size_t)G_CAST*256){
      int col = (int)(i & 127); size_t rp = i >> 7;
      int t = (int)(rp >> 10), b = (int)(rp & 1023);
      float v = (col < CC) ? q_m[((size_t)b*TT + t)*CC + col] : 0.f;
      qbf[i] = f2bf(v);
    }
    return;
  }
  // hcat region: chunks of 8 cols, cols [0,384)
  {
    const size_t nchunk = (size_t)NRB*48;
    for (size_t c = (size_t)(blk - G_RC - G_CW - G_CAST)*256 + tid; c < nchunk; c += (size_t)G_HCAT*256){
      size_t row = c / 48;
      int c0 = (int)(c - row*48) * 8;
      short8 o;
      if (c0 < 256){
        int qn = q_next[row];
        float4 v0 = *(const float4*)(emb + (size_t)qn*EMBD + c0);
        float4 v1 = *(const float4*)(emb + (size_t)qn*EMBD + c0 + 4);
        o[0]=f2bf(v0.x); o[1]=f2bf(v0.y); o[2]=f2bf(v0.z); o[3]=f2bf(v0.w);
        o[4]=f2bf(v1.x); o[5]=f2bf(v1.y); o[6]=f2bf(v1.z); o[7]=f2bf(v1.w);
      } else {
        int j0 = c0 - 256;
        #pragma unroll
        for (int jj=0;jj<8;jj++){
          int j = j0 + jj;
          o[jj] = (j < CC) ? f2bf(qmn[row*CC + j]) : (short)0;
        }
      }
      *(short8*)(Abf + row*512 + c0) = o;
    }
  }
}

// ---------------------------------------------------------------------------
// k_zz_elem: AB = qbf @ zzW^T + zz_b (MFMA); epilogue writes swizzled
//  x1a (A-frag order), pre2/cq (C-frag order), all bf16.
__global__ __launch_bounds__(256) void k_zz_elem(
    const us* __restrict__ X, const us* __restrict__ W,
    const float* __restrict__ zz_b,
    const float* __restrict__ q_m, const int* __restrict__ s_id,
    const int* __restrict__ e_id, const float* __restrict__ student_W,
    const float* __restrict__ k_diff_W, const float* __restrict__ e_disc_W,
    const float* __restrict__ d_t_p, const float* __restrict__ d_e_p,
    us* __restrict__ x1a, us* __restrict__ pre2, us* __restrict__ cqb)
{
  __shared__ __align__(16) us Asl[16][64][8];   // 16 KB
  const int tid = threadIdx.x, w = tid >> 6, l = tid & 63, q = l >> 4, r16 = l & 15;
  const int rTile = blockIdx.x*64;
  short8 bfr[2][4];
  #pragma unroll
  for (int nt=0;nt<2;nt++){
    int n = w*32 + nt*16 + r16;
    #pragma unroll
    for (int kt=0;kt<4;kt++)
      bfr[nt][kt] = *(const short8*)(W + (size_t)n*128 + kt*32 + q*8);
  }
  #pragma unroll
  for (int i=0;i<4;i++){
    int seg = i*4 + w;
    gl_lds16(&Asl[seg][l][0], X + (size_t)(rTile+l)*128 + seg*8);
  }
  floatx4 acc[4][2];
  #pragma unroll
  for (int mt=0;mt<4;mt++){
    #pragma unroll
    for (int nt=0;nt<2;nt++){ acc[mt][nt][0]=0.f; acc[mt][nt][1]=0.f; acc[mt][nt][2]=0.f; acc[mt][nt][3]=0.f; }
  }
  __syncthreads();
  #pragma unroll
  for (int kt=0;kt<4;kt++){
    short8 af[4];
    #pragma unroll
    for (int mt=0;mt<4;mt++) af[mt] = *(const short8*)&Asl[kt*4+q][mt*16+r16][0];
    #pragma unroll
    for (int mt=0;mt<4;mt++){
      #pragma unroll
      for (int nt=0;nt<2;nt++)
        acc[mt][nt] = __builtin_amdgcn_mfma_f32_16x16x32_bf16(af[mt], bfr[nt][kt], acc[mt][nt], 0,0,0);
    }
  }
  const float dt = d_t_p[0], de = d_e_p[0];
  float zzb[2]; int colv[2];
  #pragma unroll
  for (int nt=0;nt<2;nt++){
    int col = w*32 + nt*16 + r16; colv[nt] = col;
    zzb[nt] = (col < CC) ? zz_b[col] : 0.f;
  }
  const int t = rTile >> 10;           // rows of this block share t (1024 % 64 == 0)
  #pragma unroll
  for (int mt=0;mt<4;mt++){
    #pragma unroll
    for (int i=0;i<4;i++){
      int row = rTile + mt*16 + q*4 + i;
      int b = row & 1023;
      int g = b*TT + t;
      int btile = b >> 4, r = b & 15;
      int sid = s_id[b];
      int e   = e_id[g];
      float ed = fsig(e_disc_W[e]) * de;
      size_t base = ((size_t)t*64 + btile)*2048;
      #pragma unroll
      for (int nt=0;nt<2;nt++){
        int col = colv[nt];
        float x1v = 0.f, p2v = 0.f, cqv = 0.f;
        if (col < CC){
          float ab = acc[mt][nt][i] + zzb[nt];
          float sp = fsig(student_W[(size_t)sid*CC + col]);
          float kd = fsig(k_diff_W[(size_t)e*CC + col]);
          float qv = q_m[(size_t)g*CC + col];
          x1v = ab*sp;
          p2v = ed*(dt*sp - kd)*qv;
          cqv = ed*(1.f - dt)*qv;
        }
        x1a[base + (size_t)(((col>>5)*64 + ((col>>3)&3)*16 + r)*8) + (col&7)] = f2bf(x1v);
        size_t off = base + (size_t)(((col>>5)*64 + ((r>>2))*16 + (col&15))*8) + ((col>>4)&1)*4 + (r&3);
        pre2[off] = f2bf(p2v);
        cqb[off]  = f2bf(cqv);
      }
    }
  }
}

// ---------------------------------------------------------------------------
// k_mid: WAVE-SPECIALIZED producer/consumer pipeline, one barrier per interval.
// Waves 0-3 (group A): rnn1 (h1 recurrence) + Xp precompute + x2 production,
//   running one step AHEAD; each A-wave owns 32 cols (2 MFMA col-tiles).
// Waves 4-7 (group B): rnn2 (h2/GRU) for the previous step; 32 cols each.
// Mechanism: each SIMD hosts one A-wave + one B-wave at DIFFERENT pipeline
// phases -> LDS/MFMA/trans stalls interleave instead of aligning lockstep.
// Interval k: A computes step k (reads h1s[k^1], writes h1s[k&1]/x2s[k&1]);
//             B computes step k-1 (reads x2s[(k-1)&1], h2s[k&1]; writes
//             h2s[(k-1)&1]); A also exports h2(k-2) from h2s[k&1]. All
//             read-buffers are stable within the interval -> race-free.
// Accumulation order per value identical to the proven r0 kernel (absmax
// preserved). Weight regs are role-polymorphic (w[4][2][4], union ~128).
// LDS padded to 82KB -> occupancy target 1 block/CU -> VGPR cap 256
// (r3/r4 lesson: the allocator derives its VGPR clamp from LDS occupancy).
__global__ __launch_bounds__(512,1) void k_mid(
    const us* __restrict__ x1a, const us* __restrict__ pre2, const us* __restrict__ cqb,
    const us* __restrict__ Wih, const us* __restrict__ Whh,
    const us* __restrict__ Wzx, const us* __restrict__ Whx,
    const us* __restrict__ Wzh, const us* __restrict__ Whh2,
    const float* __restrict__ b_ih, const float* __restrict__ b_z, const float* __restrict__ b_h,
    const float* __restrict__ W_tg, const float* __restrict__ b_tg,
    const float* __restrict__ rtab, const int* __restrict__ r_idx,
    us* __restrict__ Abf)
{
  __shared__ __align__(16) us h1s[2][16*PCH];
  __shared__ __align__(16) us x2s[2][16*PCH];
  __shared__ __align__(16) us h2s[2][16*PCH];
  __shared__ int rint[TT*16];
  __shared__ __align__(16) us lds_pad[27680];   // -> 82KB total LDS

  const int tid = threadIdx.x, wid = tid >> 6, l = tid & 63, q = l >> 4, r16 = l & 15;
  const bool isA = wid < 4;                 // waves 0-3 producer, 4-7 consumer
  const int gw = wid & 3;
  const int bbase = blockIdx.x*16;
  const int n0 = gw*32 + r16, n1 = n0 + 16;     // this thread's two output cols
  if (Abf == (us*)0) lds_pad[tid] = (us)tid;    // opaque keep-alive for the pad

  // role-polymorphic weights: A: w[0]=W_ih, w[1]=W_hh (w[2],w[3] unused)
  //                           B: w[0]=Wzx, w[1]=Wzh, w[2]=Whx, w[3]=Whh2
  short8 w[4][2][4];
  if (isA){
    #pragma unroll
    for (int tt=0;tt<2;tt++){
      const int nn = n0 + tt*16;
      #pragma unroll
      for (int kt=0;kt<4;kt++){
        size_t wofs = (size_t)nn*128 + kt*32 + q*8;
        w[0][tt][kt] = *(const short8*)(Wih + wofs);
        w[1][tt][kt] = *(const short8*)(Whh + wofs);
      }
    }
  } else {
    #pragma unroll
    for (int tt=0;tt<2;tt++){
      const int nn = n0 + tt*16;
      #pragma unroll
      for (int kt=0;kt<4;kt++){
        size_t wofs = (size_t)nn*128 + kt*32 + q*8;
        w[0][tt][kt] = *(const short8*)(Wzx + wofs);
        w[1][tt][kt] = *(const short8*)(Wzh + wofs);
        w[2][tt][kt] = *(const short8*)(Whx + wofs);
        w[3][tt][kt] = *(const short8*)(Whh2 + wofs);
      }
    }
  }

  // init tables, bias pre-added (same float value as r0's b + rtab pick)
  const bool v0 = n0 < CC, v1 = n1 < CC;
  float ia0[2], ia1[2], ib0[2], ib1[2];
  float wg0=0.f, bg0=0.f, wg1=0.f, bg1=0.f;
  if (isA){
    ia0[0] = v0 ? b_ih[n0] + rtab[n0]     : 0.f;
    ia1[0] = v0 ? b_ih[n0] + rtab[128+n0] : 0.f;
    ia0[1] = v1 ? b_ih[n1] + rtab[n1]     : 0.f;
    ia1[1] = v1 ? b_ih[n1] + rtab[128+n1] : 0.f;
    ib0[0]=0.f; ib1[0]=0.f; ib0[1]=0.f; ib1[1]=0.f;
    wg0 = v0 ? W_tg[n0]:0.f; bg0 = v0 ? b_tg[n0]:0.f;
    wg1 = v1 ? W_tg[n1]:0.f; bg1 = v1 ? b_tg[n1]:0.f;
  } else {
    ia0[0] = v0 ? b_z[n0] + rtab[256+n0] : 0.f;
    ia1[0] = v0 ? b_z[n0] + rtab[384+n0] : 0.f;
    ia0[1] = v1 ? b_z[n1] + rtab[256+n1] : 0.f;
    ia1[1] = v1 ? b_z[n1] + rtab[384+n1] : 0.f;
    ib0[0] = v0 ? b_h[n0] + rtab[512+n0] : 0.f;
    ib1[0] = v0 ? b_h[n0] + rtab[640+n0] : 0.f;
    ib0[1] = v1 ? b_h[n1] + rtab[512+n1] : 0.f;
    ib1[1] = v1 ? b_h[n1] + rtab[640+n1] : 0.f;
  }

  for (int i = tid; i < TT*16; i += 512)
    rint[i] = r_idx[(size_t)(bbase + (i & 15))*TT + (i >> 4)];
  for (int i = tid; i < 16*PCH; i += 512){ h1s[1][i] = 0; h2s[1][i] = 0; }

  short8 x1c[4]; short8 pc8, cc8;
  if (isA){
    size_t base = (size_t)blockIdx.x*2048;   // t=0 tile
    #pragma unroll
    for (int kt=0;kt<4;kt++)
      x1c[kt] = *(const short8*)(x1a + base + (size_t)(kt*64 + q*16 + r16)*8);
    size_t cofs = base + (size_t)(gw*64 + q*16 + r16)*8;
    pc8 = *(const short8*)(pre2 + cofs);     // [0..3]=tile0, [4..7]=tile1
    cc8 = *(const short8*)(cqb + cofs);
  }
  __syncthreads();

  floatx4 accx0, accx1;
  if (isA){
    int4 rs = *(const int4*)&rint[q*4];
    accx0[0] = rs.x ? ia1[0] : ia0[0];  accx1[0] = rs.x ? ia1[1] : ia0[1];
    accx0[1] = rs.y ? ia1[0] : ia0[0];  accx1[1] = rs.y ? ia1[1] : ia0[1];
    accx0[2] = rs.z ? ia1[0] : ia0[0];  accx1[2] = rs.z ? ia1[1] : ia0[1];
    accx0[3] = rs.w ? ia1[0] : ia0[0];  accx1[3] = rs.w ? ia1[1] : ia0[1];
    #pragma unroll
    for (int kt=0;kt<4;kt++){
      accx0 = __builtin_amdgcn_mfma_f32_16x16x32_bf16(x1c[kt], w[0][0][kt], accx0, 0,0,0);
      accx1 = __builtin_amdgcn_mfma_f32_16x16x32_bf16(x1c[kt], w[0][1][kt], accx1, 0,0,0);
    }
  }
  floatx4 hold0, hold1;
  hold0[0]=0.f; hold0[1]=0.f; hold0[2]=0.f; hold0[3]=0.f;
  hold1[0]=0.f; hold1[1]=0.f; hold1[2]=0.f; hold1[3]=0.f;

  for (int k=0; k<=TT; ++k){
    const int pA = k & 1;
    if (isA){
      // ---- prefetch step k+1 inputs (consumed at bottom of this interval)
      short8 x1n[4]; short8 pcn, ccn;
      if (k+1 < TT){
        size_t base = ((size_t)(k+1)*64 + blockIdx.x)*2048;
        #pragma unroll
        for (int kt=0;kt<4;kt++)
          x1n[kt] = *(const short8*)(x1a + base + (size_t)(kt*64 + q*16 + r16)*8);
        size_t cofs = base + (size_t)(gw*64 + q*16 + r16)*8;
        pcn = *(const short8*)(pre2 + cofs);
        ccn = *(const short8*)(cqb + cofs);
      }
      if (k < TT){
        // ---- h1 recurrence for step k + x2 production
        short8 fr1[4];
        #pragma unroll
        for (int kt=0;kt<4;kt++)
          fr1[kt] = *(const short8*)&h1s[pA^1][r16*PCH + kt*32 + q*8];
        floatx4 a0 = accx0, a1 = accx1;
        #pragma unroll
        for (int kt=0;kt<4;kt++){
          a0 = __builtin_amdgcn_mfma_f32_16x16x32_bf16(fr1[kt], w[1][0][kt], a0, 0,0,0);
          a1 = __builtin_amdgcn_mfma_f32_16x16x32_bf16(fr1[kt], w[1][1][kt], a1, 0,0,0);
        }
        float g0 = fsig((float)k*wg0 + bg0);
        float g1 = fsig((float)k*wg1 + bg1);
        #pragma unroll
        for (int i=0;i<4;i++){
          float h1v0 = ftanh(a0[i]) * g0;
          h1s[pA][(q*4+i)*PCH + n0] = f2bfh(h1v0);
          float xv0 = bf2f((us)pc8[i]) + bf2f((us)cc8[i])*h1v0;
          x2s[pA][(q*4+i)*PCH + n0] = f2bfh(xv0);
          float h1v1 = ftanh(a1[i]) * g1;
          h1s[pA][(q*4+i)*PCH + n1] = f2bfh(h1v1);
          float xv1 = bf2f((us)pc8[4+i]) + bf2f((us)cc8[4+i])*h1v1;
          x2s[pA][(q*4+i)*PCH + n1] = f2bfh(xv1);
        }
      }
      // ---- export h2(k-2) (h2s[pA] is read-only this interval)
      if (k >= 2){
        int row = tid >> 4, cs = tid & 15;
        short8 hv8 = *(const short8*)&h2s[pA][row*PCH + cs*8];
        *(short8*)(Abf + ((size_t)(bbase + row)*TT + (k-2))*512 + 384 + cs*8) = hv8;
      }
      // ---- Xp(k+1) from prefetched x1
      if (k+1 < TT){
        int4 rs = *(const int4*)&rint[(k+1)*16 + q*4];
        accx0[0] = rs.x ? ia1[0] : ia0[0];  accx1[0] = rs.x ? ia1[1] : ia0[1];
        accx0[1] = rs.y ? ia1[0] : ia0[0];  accx1[1] = rs.y ? ia1[1] : ia0[1];
        accx0[2] = rs.z ? ia1[0] : ia0[0];  accx1[2] = rs.z ? ia1[1] : ia0[1];
        accx0[3] = rs.w ? ia1[0] : ia0[0];  accx1[3] = rs.w ? ia1[1] : ia0[1];
        #pragma unroll
        for (int kt=0;kt<4;kt++){
          accx0 = __builtin_amdgcn_mfma_f32_16x16x32_bf16(x1n[kt], w[0][0][kt], accx0, 0,0,0);
          accx1 = __builtin_amdgcn_mfma_f32_16x16x32_bf16(x1n[kt], w[0][1][kt], accx1, 0,0,0);
        }
        pc8 = pcn; cc8 = ccn;
      }
    } else if (k >= 1){
      // ---- group B: h2/GRU recurrence for step t = k-1
      const int t = k-1, pB = t & 1;
      short8 fx[4], fh[4];
      #pragma unroll
      for (int kt=0;kt<4;kt++){
        fx[kt] = *(const short8*)&x2s[pB][r16*PCH + kt*32 + q*8];
        fh[kt] = *(const short8*)&h2s[pB^1][r16*PCH + kt*32 + q*8];
      }
      int4 rs = *(const int4*)&rint[t*16 + q*4];
      floatx4 az0, az1, ah0, ah1;
      az0[0] = rs.x ? ia1[0] : ia0[0];  ah0[0] = rs.x ? ib1[0] : ib0[0];
      az0[1] = rs.y ? ia1[0] : ia0[0];  ah0[1] = rs.y ? ib1[0] : ib0[0];
      az0[2] = rs.z ? ia1[0] : ia0[0];  ah0[2] = rs.z ? ib1[0] : ib0[0];
      az0[3] = rs.w ? ia1[0] : ia0[0];  ah0[3] = rs.w ? ib1[0] : ib0[0];
      az1[0] = rs.x ? ia1[1] : ia0[1];  ah1[0] = rs.x ? ib1[1] : ib0[1];
      az1[1] = rs.y ? ia1[1] : ia0[1];  ah1[1] = rs.y ? ib1[1] : ib0[1];
      az1[2] = rs.z ? ia1[1] : ia0[1];  ah1[2] = rs.z ? ib1[1] : ib0[1];
      az1[3] = rs.w ? ia1[1] : ia0[1];  ah1[3] = rs.w ? ib1[1] : ib0[1];
      #pragma unroll
      for (int kt=0;kt<4;kt++){
        az0 = __builtin_amdgcn_mfma_f32_16x16x32_bf16(fx[kt], w[0][0][kt], az0, 0,0,0);
        az0 = __builtin_amdgcn_mfma_f32_16x16x32_bf16(fh[kt], w[1][0][kt], az0, 0,0,0);
        ah0 = __builtin_amdgcn_mfma_f32_16x16x32_bf16(fx[kt], w[2][0][kt], ah0, 0,0,0);
        ah0 = __builtin_amdgcn_mfma_f32_16x16x32_bf16(fh[kt], w[3][0][kt], ah0, 0,0,0);
        az1 = __builtin_amdgcn_mfma_f32_16x16x32_bf16(fx[kt], w[0][1][kt], az1, 0,0,0);
        az1 = __builtin_amdgcn_mfma_f32_16x16x32_bf16(fh[kt], w[1][1][kt], az1, 0,0,0);
        ah1 = __builtin_amdgcn_mfma_f32_16x16x32_bf16(fx[kt], w[2][1][kt], ah1, 0,0,0);
        ah1 = __builtin_amdgcn_mfma_f32_16x16x32_bf16(fh[kt], w[3][1][kt], ah1, 0,0,0);
      }
      #pragma unroll
      for (int i=0;i<4;i++){
        float z0  = fsig(az0[i]);
        float th0 = ftanh(ah0[i]);
        hold0[i] += z0*(th0 - hold0[i]);
        h2s[pB][(q*4+i)*PCH + n0] = f2bfh(hold0[i]);
        float z1  = fsig(az1[i]);
        float th1 = ftanh(ah1[i]);
        hold1[i] += z1*(th1 - hold1[i]);
        h2s[pB][(q*4+i)*PCH + n1] = f2bfh(hold1[i]);
      }
    }
    __syncthreads();
  }
  // final export t = TT-1
  if (tid < 256){
    int row = tid >> 4, cs = tid & 15;
    short8 hv8 = *(const short8*)&h2s[(TT-1)&1][row*PCH + cs*8];
    *(short8*)(Abf + ((size_t)(bbase + row)*TT + (TT-1))*512 + 384 + cs*8) = hv8;
  }
}

// ---------------------------------------------------------------------------
// k_out: o1 = sigmoid(Abf @ p1bf^T + p1_b) kept in LDS (bf16),
//        o2 = sigmoid(o1 @ p2bf^T + p2_b), out = sigmoid(o2 @ p3 + p3_b).
__global__ __launch_bounds__(256) void k_out(
    const us* __restrict__ Abf, const us* __restrict__ p1bf,
    const float* __restrict__ p1_b, const us* __restrict__ p2bf,
    const float* __restrict__ p2_b, const float* __restrict__ p3_W,
    const float* __restrict__ p3_b, float* __restrict__ out)
{
  __shared__ __align__(16) us smem[20480];   // 40 KB: Asl(4096) + Bsl(16384); o1s aliases (16896)
  __shared__ float red[64][4];
  us* Asl = smem;            // [seg<8][m<64][8]
  us* Bsl = smem + 4096;     // [seg<8][n<256][8]
  us* o1s = smem;            // [row<64][264] (aliased after phase 1)
  const int tid = threadIdx.x;
  const int w = tid >> 6, l = tid & 63;
  const int q = l >> 4, r16 = l & 15;
  const int rTile = blockIdx.x * 64;
  floatx4 acc[4][4];
  #pragma unroll
  for (int a=0;a<4;a++){
    #pragma unroll
    for (int b=0;b<4;b++){ acc[a][b][0]=0.f; acc[a][b][1]=0.f; acc[a][b][2]=0.f; acc[a][b][3]=0.f; }
  }
  for (int c = 0; c < 8; c++){
    const int k0 = c*64;
    #pragma unroll
    for (int i=0;i<2;i++){
      int u = i*256 + tid; int seg = u>>6, m = u&63;
      gl_lds16(&Asl[(seg*64 + m)*8], Abf + (size_t)(rTile+m)*512 + k0 + seg*8);
    }
    #pragma unroll
    for (int i=0;i<8;i++){
      int u = i*256 + tid; int seg = u>>8, nn = u&255;
      gl_lds16(&Bsl[(seg*256 + nn)*8], p1bf + (size_t)nn*512 + k0 + seg*8);
    }
    __syncthreads();
    #pragma unroll
    for (int ks=0; ks<2; ks++){
      int seg = ks*4 + q;
      short8 af[4], bfr[4];
      #pragma unroll
      for (int mt=0;mt<4;mt++) af[mt] = *(const short8*)&Asl[(seg*64 + mt*16 + r16)*8];
      #pragma unroll
      for (int nt=0;nt<4;nt++) bfr[nt] = *(const short8*)&Bsl[(seg*256 + w*64 + nt*16 + r16)*8];
      #pragma unroll
      for (int mt=0;mt<4;mt++){
        #pragma unroll
        for (int nt=0;nt<4;nt++)
          acc[mt][nt] = __builtin_amdgcn_mfma_f32_16x16x32_bf16(af[mt], bfr[nt], acc[mt][nt], 0,0,0);
      }
    }
    __syncthreads();
  }
  // ---- write o1 (sigmoid) into LDS, row-major pitch 264
  #pragma unroll
  for (int nt=0;nt<4;nt++){
    int col = w*64 + nt*16 + r16;
    float bb = p1_b[col];
    #pragma unroll
    for (int mt=0;mt<4;mt++){
      #pragma unroll
      for (int i=0;i<4;i++)
        o1s[(mt*16 + q*4 + i)*264 + col] = f2bf(fsig(acc[mt][nt][i] + bb));
    }
  }
  __syncthreads();
  // ---- phase 2: o2 GEMM (M=64, N=128, K=256) + p3 reduction
  short8 bf2[2][8];
  #pragma unroll
  for (int nt=0;nt<2;nt++){
    int n2 = w*32 + nt*16 + r16;
    #pragma unroll
    for (int kt=0;kt<8;kt++)
      bf2[nt][kt] = *(const short8*)(p2bf + (size_t)n2*256 + kt*32 + q*8);
  }
  floatx4 ac2[4][2];
  #pragma unroll
  for (int mt=0;mt<4;mt++){
    #pragma unroll
    for (int nt=0;nt<2;nt++){ ac2[mt][nt][0]=0.f; ac2[mt][nt][1]=0.f; ac2[mt][nt][2]=0.f; ac2[mt][nt][3]=0.f; }
  }
  #pragma unroll
  for (int kt=0;kt<8;kt++){
    short8 af[4];
    #pragma unroll
    for (int mt=0;mt<4;mt++) af[mt] = *(const short8*)&o1s[(mt*16 + r16)*264 + kt*32 + q*8];
    #pragma unroll
    for (int mt=0;mt<4;mt++){
      #pragma unroll
      for (int nt=0;nt<2;nt++)
        ac2[mt][nt] = __builtin_amdgcn_mfma_f32_16x16x32_bf16(af[mt], bf2[nt][kt], ac2[mt][nt], 0,0,0);
    }
  }
  const int n0 = w*32 + r16, n1 = n0 + 16;
  const float pb0 = (n0<CC)? p2_b[n0]:0.f, pb1 = (n1<CC)? p2_b[n1]:0.f;
  const float p30 = (n0<CC)? p3_W[n0]:0.f, p31 = (n1<CC)? p3_W[n1]:0.f;
  #pragma unroll
  for (int mt=0;mt<4;mt++){
    #pragma unroll
    for (int i=0;i<4;i++){
      float s = fsig(ac2[mt][0][i]+pb0)*p30 + fsig(ac2[mt][1][i]+pb1)*p31;
      s += __shfl_xor(s,1,16); s += __shfl_xor(s,2,16);
      s += __shfl_xor(s,4,16); s += __shfl_xor(s,8,16);
      if (r16==0) red[mt*16 + q*4 + i][w] = s;
    }
  }
  __syncthreads();
  if (tid < 64){
    float o = red[tid][0]+red[tid][1]+red[tid][2]+red[tid][3] + p3_b[0];
    out[rTile + tid] = fsig(o);
  }
}

// ---------------------------------------------------------------------------
extern "C" void kernel_launch(void* const* d_in, const int* in_sizes, int n_in,
                              void* d_out, int out_size, void* d_ws, size_t ws_size,
                              hipStream_t stream) {
  const float* q_m       = (const float*)d_in[0];
  const float* q_m_next  = (const float*)d_in[1];
  const int*   s_id      = (const int*)d_in[3];
  const int*   e_id      = (const int*)d_in[4];
  const int*   r_idx     = (const int*)d_in[5];
  const int*   q_next    = (const int*)d_in[6];
  const float* emb_problem = (const float*)d_in[8];
  const float* student_W = (const float*)d_in[9];
  const float* k_diff_W  = (const float*)d_in[10];
  const float* e_disc_W  = (const float*)d_in[11];
  const float* answer_W  = (const float*)d_in[12];
  const float* zz_W      = (const float*)d_in[13];
  const float* zz_b      = (const float*)d_in[14];
  const float* d_t       = (const float*)d_in[15];
  const float* d_e       = (const float*)d_in[16];
  const float* W_ih      = (const float*)d_in[17];
  const float* b_ih      = (const float*)d_in[18];
  const float* W_hh      = (const float*)d_in[19];
  const float* W_tg      = (const float*)d_in[21];
  const float* b_tg      = (const float*)d_in[22];
  const float* W_z       = (const float*)d_in[23];
  const float* b_z       = (const float*)d_in[24];
  const float* W_h       = (const float*)d_in[25];
  const float* b_h       = (const float*)d_in[26];
  const float* p1_W      = (const float*)d_in[27];
  const float* p1_b      = (const float*)d_in[28];
  const float* p2_W      = (const float*)d_in[29];
  const float* p2_b      = (const float*)d_in[30];
  const float* p3_W      = (const float*)d_in[31];
  const float* p3_b      = (const float*)d_in[32];

  float* ws   = (float*)d_ws;
  float* rtab = ws;                                   // 1024 f32
  us* qbf  = (us*)(ws + 1024);                        // [NRB][128]
  us* x1a  = qbf  + (size_t)NRB*128;                  // swizzled [t][btile][2048]
  us* pre2 = x1a  + (size_t)NRB*128;
  us* cqb  = pre2 + (size_t)NRB*128;
  us* Abf  = cqb  + (size_t)NRB*128;                  // [NRB][512]
  us* wts  = Abf  + (size_t)NRB*512;                  // 7*[128][128]
  us* p1bf = wts  + 7*16384;                          // [256][512]
  us* p2bf = p1bf + 256*512;                          // [128][256]

  const us* zzWbf  = wts + 0*16384;
  const us* Wih123 = wts + 1*16384;
  const us* Wz123  = wts + 2*16384;
  const us* Wh123  = wts + 3*16384;
  const us* Whhbf  = wts + 4*16384;
  const us* Wzhbf  = wts + 5*16384;
  const us* Whh2bf = wts + 6*16384;

  hipLaunchKernelGGL(k_pre, dim3(G_PRE), dim3(256), 0, stream,
                     W_ih, W_z, W_h, answer_W, zz_W, W_hh, p1_W, p2_W,
                     emb_problem, q_next, q_m_next, q_m,
                     rtab, wts, p1bf, p2bf, qbf, Abf);
  hipLaunchKernelGGL(k_zz_elem, dim3(NRB/64), dim3(256), 0, stream,
                     qbf, zzWbf, zz_b, q_m, s_id, e_id, student_W, k_diff_W,
                     e_disc_W, d_t, d_e, x1a, pre2, cqb);
  hipLaunchKernelGGL(k_mid, dim3(BB/16), dim3(512), 0, stream,
                     x1a, pre2, cqb, Wih123, Whhbf, Wz123, Wh123, Wzhbf, Whh2bf,
                     b_ih, b_z, b_h, W_tg, b_tg, rtab, r_idx, Abf);
  hipLaunchKernelGGL(k_out, dim3(NRB/64), dim3(256), 0, stream,
                     Abf, p1bf, p1_b, p2bf, p2_b, p3_W, p3_b, (float*)d_out);
}